// Round 1
// baseline (318.413 us; speedup 1.0000x reference)
//
#include <hip/hip_runtime.h>

typedef unsigned short u16;
typedef __bf16 bf16x8 __attribute__((ext_vector_type(8)));
typedef float floatx4 __attribute__((ext_vector_type(4)));

#define B_ 4
#define SEQ 2048
#define DIM 1024

__device__ __forceinline__ u16 f2bf(float f) {
    unsigned u = __builtin_bit_cast(unsigned, f);
    u += 0x7FFFu + ((u >> 16) & 1u);
    return (u16)(u >> 16);
}
__device__ __forceinline__ float bf2f(u16 h) {
    unsigned u = ((unsigned)h) << 16;
    return __builtin_bit_cast(float, u);
}

#define GPTR(p) ((const __attribute__((address_space(1))) void*)(p))
#define LPTR(p) ((__attribute__((address_space(3))) void*)(p))

// ---------------- convert x fp32 -> bf16 ----------------
__global__ __launch_bounds__(256) void convert_x(const float4* __restrict__ x,
                                                 ushort4* __restrict__ xb) {
    int i = blockIdx.x * 256 + threadIdx.x;  // 2M float4s
    float4 v = x[i];
    ushort4 o;
    o.x = f2bf(v.x); o.y = f2bf(v.y); o.z = f2bf(v.z); o.w = f2bf(v.w);
    xb[i] = o;
}

// ---------------- transpose W [k][n] fp32 -> Wt [n][k] bf16 ----------------
__global__ __launch_bounds__(256) void transpose_w(const float* __restrict__ Wq,
                                                   const float* __restrict__ Wk,
                                                   const float* __restrict__ Wv,
                                                   u16* __restrict__ Wt) {
    __shared__ u16 t[64][66];
    const int z = blockIdx.z;
    const float* W = (z == 0) ? Wq : ((z == 1) ? Wk : Wv);
    u16* out = Wt + (size_t)z * DIM * DIM;
    const int tx = threadIdx.x, ty = threadIdx.y;  // (32,8)
    const int k0 = blockIdx.x * 64, n0 = blockIdx.y * 64;
#pragma unroll
    for (int j = 0; j < 8; j++) {
        int k = ty + 8 * j;
        float2 v = *(const float2*)(W + (size_t)(k0 + k) * DIM + n0 + 2 * tx);
        t[2 * tx][k] = f2bf(v.x);
        t[2 * tx + 1][k] = f2bf(v.y);
    }
    __syncthreads();
#pragma unroll
    for (int j = 0; j < 8; j++) {
        int n = ty + 8 * j;
        ushort2 o;
        o.x = t[n][2 * tx];
        o.y = t[n][2 * tx + 1];
        *(ushort2*)(out + (size_t)(n0 + n) * DIM + k0 + 2 * tx) = o;
    }
}

// ---------------- transpose V [s][d] bf16 -> Vt [d][s] bf16 (per batch) ------
__global__ __launch_bounds__(256) void transpose_v(const u16* __restrict__ V,
                                                   u16* __restrict__ Vt) {
    __shared__ u16 t[64][66];
    const int z = blockIdx.z;
    const u16* Vb = V + (size_t)z * SEQ * DIM;
    u16* Ob = Vt + (size_t)z * DIM * SEQ;
    const int tx = threadIdx.x, ty = threadIdx.y;  // (32,8)
    const int s0 = blockIdx.x * 64, d0 = blockIdx.y * 64;
#pragma unroll
    for (int j = 0; j < 8; j++) {
        int s = ty + 8 * j;
        ushort2 v = *(const ushort2*)(Vb + (size_t)(s0 + s) * DIM + d0 + 2 * tx);
        t[2 * tx][s] = v.x;
        t[2 * tx + 1][s] = v.y;
    }
    __syncthreads();
#pragma unroll
    for (int j = 0; j < 8; j++) {
        int d = ty + 8 * j;
        ushort2 o;
        o.x = t[d][2 * tx];
        o.y = t[d][2 * tx + 1];
        *(ushort2*)(Ob + (size_t)(d0 + d) * SEQ + s0 + 2 * tx) = o;
    }
}

// ---------------- generic 128x128 bf16 GEMM, B given transposed [n][k] -------
// MODE 0: QKV projection (+bias, bf16 out)
// MODE 1: scores (x scale, bf16 out, causal tile skip)
// MODE 2: PV (fp32 out, K limited to (q_tile+1)*128)
template <int MODE>
__global__ __launch_bounds__(256) void gemm_bt(
    const u16* __restrict__ A, const u16* __restrict__ Bt, void* __restrict__ Cv,
    const float* __restrict__ b0, const float* __restrict__ b1, const float* __restrict__ b2,
    int lda, int ldb, int ldc, int K, float scale,
    long long sAz, long long sBz, long long sCz) {
    if (MODE == 1 && blockIdx.x > blockIdx.y) return;  // fully-masked tile

    __shared__ u16 lsA[128 * 32];
    __shared__ u16 lsB[128 * 32];
    const int tid = threadIdx.x;
    const int wave = tid >> 6, lane = tid & 63;
    const int quad = lane >> 4, l15 = lane & 15;
    const int wm = (wave >> 1) * 64, wn = (wave & 1) * 64;
    const int z = blockIdx.z;

    const u16* Ab = A + (long long)z * sAz + (size_t)blockIdx.y * 128 * lda;
    const u16* Bb = Bt + (long long)z * sBz + (size_t)blockIdx.x * 128 * ldb;
    const int srow = tid >> 2;
    const int scol = (tid & 3) * 8;
    const u16* gA0 = Ab + (size_t)srow * lda + scol;
    const u16* gA1 = gA0 + (size_t)64 * lda;
    const u16* gB0 = Bb + (size_t)srow * ldb + scol;
    const u16* gB1 = gB0 + (size_t)64 * ldb;
    u16* lA0 = lsA + wave * 512;
    u16* lA1 = lsA + 2048 + wave * 512;
    u16* lB0 = lsB + wave * 512;
    u16* lB1 = lsB + 2048 + wave * 512;

    floatx4 acc[4][4];
#pragma unroll
    for (int i = 0; i < 4; i++)
#pragma unroll
        for (int j = 0; j < 4; j++) {
            floatx4 zz = {0.f, 0.f, 0.f, 0.f};
            acc[i][j] = zz;
        }

    const int Kt = (MODE == 2) ? (int)((blockIdx.y + 1) * 128) : K;
    for (int k0 = 0; k0 < Kt; k0 += 32) {
        __builtin_amdgcn_global_load_lds(GPTR(gA0), LPTR(lA0), 16, 0, 0);
        __builtin_amdgcn_global_load_lds(GPTR(gA1), LPTR(lA1), 16, 0, 0);
        __builtin_amdgcn_global_load_lds(GPTR(gB0), LPTR(lB0), 16, 0, 0);
        __builtin_amdgcn_global_load_lds(GPTR(gB1), LPTR(lB1), 16, 0, 0);
        gA0 += 32; gA1 += 32; gB0 += 32; gB1 += 32;
        __syncthreads();

        bf16x8 af[4], bfr[4];
#pragma unroll
        for (int i = 0; i < 4; i++) {
            af[i] = *(const bf16x8*)(lsA + (wm + i * 16 + l15) * 32 + quad * 8);
            bfr[i] = *(const bf16x8*)(lsB + (wn + i * 16 + l15) * 32 + quad * 8);
        }
#pragma unroll
        for (int i = 0; i < 4; i++)
#pragma unroll
            for (int j = 0; j < 4; j++)
                acc[i][j] = __builtin_amdgcn_mfma_f32_16x16x32_bf16(af[i], bfr[j], acc[i][j], 0, 0, 0);
        __syncthreads();
    }

    // epilogue: C/D layout col=lane&15, row=quad*4+r  [verified m89/m91]
    const int m0 = blockIdx.y * 128 + wm + quad * 4;
    const int n0 = blockIdx.x * 128 + wn + l15;
    if (MODE == 0) {
        u16* Cb = (u16*)Cv + (long long)z * sCz;
        const float* bias = (z == 0) ? b0 : ((z == 1) ? b1 : b2);
#pragma unroll
        for (int j = 0; j < 4; j++) {
            float bv_ = bias[n0 + j * 16];
#pragma unroll
            for (int i = 0; i < 4; i++)
#pragma unroll
                for (int r = 0; r < 4; r++)
                    Cb[(size_t)(m0 + i * 16 + r) * ldc + (n0 + j * 16)] = f2bf(acc[i][j][r] + bv_);
        }
    } else if (MODE == 1) {
        u16* Cb = (u16*)Cv + (long long)z * sCz;
#pragma unroll
        for (int j = 0; j < 4; j++)
#pragma unroll
            for (int i = 0; i < 4; i++)
#pragma unroll
                for (int r = 0; r < 4; r++)
                    Cb[(size_t)(m0 + i * 16 + r) * ldc + (n0 + j * 16)] = f2bf(acc[i][j][r] * scale);
    } else {
        float* Cf = (float*)Cv + (long long)z * sCz;
#pragma unroll
        for (int j = 0; j < 4; j++)
#pragma unroll
            for (int i = 0; i < 4; i++)
#pragma unroll
                for (int r = 0; r < 4; r++)
                    Cf[(size_t)(m0 + i * 16 + r) * ldc + (n0 + j * 16)] = acc[i][j][r];
    }
}

// ---------------- causal softmax over bf16 scores, in place -> P bf16 --------
__global__ __launch_bounds__(256) void softmax_causal(u16* __restrict__ S) {
    const int q = blockIdx.x, b = blockIdx.y, tid = threadIdx.x;
    u16* row = S + ((size_t)b * SEQ + q) * SEQ;
    const int L = q + 1;                    // valid keys
    const int Z = ((q >> 7) + 1) << 7;      // zero-fill bound = PV's K_eff
    __shared__ float red[4];

    float m = -1e30f;
    for (int k = tid; k < L; k += 256) m = fmaxf(m, bf2f(row[k]));
#pragma unroll
    for (int o = 32; o > 0; o >>= 1) m = fmaxf(m, __shfl_xor(m, o));
    if ((tid & 63) == 0) red[tid >> 6] = m;
    __syncthreads();
    m = fmaxf(fmaxf(red[0], red[1]), fmaxf(red[2], red[3]));

    float s = 0.f;
    for (int k = tid; k < L; k += 256) s += __expf(bf2f(row[k]) - m);
#pragma unroll
    for (int o = 32; o > 0; o >>= 1) s += __shfl_xor(s, o);
    __syncthreads();
    if ((tid & 63) == 0) red[tid >> 6] = s;
    __syncthreads();
    s = red[0] + red[1] + red[2] + red[3];
    const float inv = 1.0f / s;

    for (int k = tid; k < Z; k += 256) {
        float p = (k < L) ? __expf(bf2f(row[k]) - m) * inv : 0.f;
        row[k] = f2bf(p);
    }
}

extern "C" void kernel_launch(void* const* d_in, const int* in_sizes, int n_in,
                              void* d_out, int out_size, void* d_ws, size_t ws_size,
                              hipStream_t stream) {
    const float* x = (const float*)d_in[0];
    const float* Wq = (const float*)d_in[1];
    const float* bq = (const float*)d_in[2];
    const float* Wk = (const float*)d_in[3];
    const float* bk = (const float*)d_in[4];
    const float* Wv = (const float*)d_in[5];
    const float* bv = (const float*)d_in[6];
    float* out = (float*)d_out;

    char* ws = (char*)d_ws;
    const size_t MB = 1024ull * 1024ull;
    // layout: [0,32MB) early: xb(16MB)+Wt(6MB) ; late: S/P bf16 (32MB)
    //         [32,80MB) Q,K,V bf16 ; [80,96MB) Vt bf16
    u16* S = (u16*)ws;
    u16* xb = (u16*)ws;
    u16* Wt = (u16*)(ws + 16 * MB);
    u16* QKV = (u16*)(ws + 32 * MB);
    u16* Vt = (u16*)(ws + 80 * MB);
    const size_t MAT = (size_t)B_ * SEQ * DIM;  // 8M elements
    u16* Q = QKV;
    u16* Km = QKV + MAT;
    u16* V = QKV + 2 * MAT;

    const float scale = 0.03125f;  // 1/sqrt(1024)

    convert_x<<<8192, 256, 0, stream>>>((const float4*)x, (ushort4*)xb);
    transpose_w<<<dim3(16, 16, 3), dim3(32, 8), 0, stream>>>(Wq, Wk, Wv, Wt);
    // QKV projection: C[8192,1024] = xb @ Wt^T + bias  (z -> q,k,v)
    gemm_bt<0><<<dim3(8, 64, 3), 256, 0, stream>>>(
        xb, Wt, QKV, bq, bk, bv, DIM, DIM, DIM, DIM, 0.f,
        0LL, (long long)DIM * DIM, (long long)MAT);
    // scores: per batch, S[2048,2048] = Q @ K^T * scale (lower-tri tiles)
    gemm_bt<1><<<dim3(16, 16, 4), 256, 0, stream>>>(
        Q, Km, S, nullptr, nullptr, nullptr, DIM, DIM, SEQ, DIM, scale,
        (long long)SEQ * DIM, (long long)SEQ * DIM, (long long)SEQ * SEQ);
    softmax_causal<<<dim3(SEQ, B_), 256, 0, stream>>>(S);
    transpose_v<<<dim3(32, 16, 4), dim3(32, 8), 0, stream>>>(V, Vt);
    // context: per batch, out[2048,1024] = P @ Vt^T (K limited per q-tile)
    gemm_bt<2><<<dim3(8, 16, 4), 256, 0, stream>>>(
        S, Vt, out, nullptr, nullptr, nullptr, SEQ, SEQ, DIM, SEQ, 1.f,
        (long long)SEQ * SEQ, (long long)DIM * SEQ, (long long)SEQ * DIM);
}

// Round 2
// 314.034 us; speedup vs baseline: 1.0139x; 1.0139x over previous
//
#include <hip/hip_runtime.h>

typedef unsigned short u16;
typedef __bf16 bf16x8 __attribute__((ext_vector_type(8)));
typedef float floatx4 __attribute__((ext_vector_type(4)));

#define B_ 4
#define SEQ 2048
#define DIM 1024

__device__ __forceinline__ u16 f2bf(float f) {
    unsigned u = __builtin_bit_cast(unsigned, f);
    u += 0x7FFFu + ((u >> 16) & 1u);
    return (u16)(u >> 16);
}
__device__ __forceinline__ float bf2f(u16 h) {
    unsigned u = ((unsigned)h) << 16;
    return __builtin_bit_cast(float, u);
}

#define GPTR(p) ((const __attribute__((address_space(1))) void*)(p))
#define LPTR(p) ((__attribute__((address_space(3))) void*)(p))

// ---------------- convert x fp32 -> bf16 ----------------
__global__ __launch_bounds__(256) void convert_x(const float4* __restrict__ x,
                                                 ushort4* __restrict__ xb) {
    int i = blockIdx.x * 256 + threadIdx.x;  // 2M float4s
    float4 v = x[i];
    ushort4 o;
    o.x = f2bf(v.x); o.y = f2bf(v.y); o.z = f2bf(v.z); o.w = f2bf(v.w);
    xb[i] = o;
}

// ---------------- transpose W [k][n] fp32 -> Wt [n][k] bf16 ----------------
__global__ __launch_bounds__(256) void transpose_w(const float* __restrict__ Wq,
                                                   const float* __restrict__ Wk,
                                                   const float* __restrict__ Wv,
                                                   u16* __restrict__ Wt) {
    __shared__ u16 t[64][66];
    const int z = blockIdx.z;
    const float* W = (z == 0) ? Wq : ((z == 1) ? Wk : Wv);
    u16* out = Wt + (size_t)z * DIM * DIM;
    const int tx = threadIdx.x, ty = threadIdx.y;  // (32,8)
    const int k0 = blockIdx.x * 64, n0 = blockIdx.y * 64;
#pragma unroll
    for (int j = 0; j < 8; j++) {
        int k = ty + 8 * j;
        float2 v = *(const float2*)(W + (size_t)(k0 + k) * DIM + n0 + 2 * tx);
        t[2 * tx][k] = f2bf(v.x);
        t[2 * tx + 1][k] = f2bf(v.y);
    }
    __syncthreads();
#pragma unroll
    for (int j = 0; j < 8; j++) {
        int n = ty + 8 * j;
        ushort2 o;
        o.x = t[n][2 * tx];
        o.y = t[n][2 * tx + 1];
        *(ushort2*)(out + (size_t)(n0 + n) * DIM + k0 + 2 * tx) = o;
    }
}

// ---------------- generic 128x128 bf16 GEMM, B given transposed [n][k] -------
// MODE 0: QKV projection (+bias). z<2 -> bf16 C; z==2 -> writes V^T to VtOut.
// MODE 1: scores (x scale, bf16 out, causal tile skip, heavy-first)
// MODE 2: PV (fp32 out, K limited to (q_tile+1)*128, heavy-first)
template <int MODE>
__global__ __launch_bounds__(256) void gemm_bt(
    const u16* __restrict__ A, const u16* __restrict__ Bt, void* __restrict__ Cv,
    const float* __restrict__ b0, const float* __restrict__ b1, const float* __restrict__ b2,
    u16* __restrict__ VtOut,
    int lda, int ldb, int ldc, int K, float scale,
    long long sAz, long long sBz, long long sCz) {
    const int yb = (MODE == 0) ? blockIdx.y : (gridDim.y - 1 - blockIdx.y);
    if (MODE == 1 && (int)blockIdx.x > yb) return;  // fully-masked tile

    __shared__ union {
        u16 stage[2][128 * 32];  // [0]=A, [1]=B  (16 KB)
        u16 epN[64 * 136];       // epilogue, row-major chunk (17.0 KB)
        u16 epT[128 * 72];       // epilogue, col-major chunk for V^T (18.4 KB)
    } sm;
    u16* lsA = sm.stage[0];
    u16* lsB = sm.stage[1];

    const int tid = threadIdx.x;
    const int wave = tid >> 6, lane = tid & 63;
    const int quad = lane >> 4, l15 = lane & 15;
    const int wm = (wave >> 1) * 64, wn = (wave & 1) * 64;
    const int z = blockIdx.z;

    const u16* Ab = A + (long long)z * sAz + (size_t)yb * 128 * lda;
    const u16* Bb = Bt + (long long)z * sBz + (size_t)blockIdx.x * 128 * ldb;
    const int srow = tid >> 2;
    const int scol = (tid & 3) * 8;
    const u16* gA0 = Ab + (size_t)srow * lda + scol;
    const u16* gA1 = gA0 + (size_t)64 * lda;
    const u16* gB0 = Bb + (size_t)srow * ldb + scol;
    const u16* gB1 = gB0 + (size_t)64 * ldb;
    u16* lA0 = lsA + wave * 512;
    u16* lA1 = lsA + 2048 + wave * 512;
    u16* lB0 = lsB + wave * 512;
    u16* lB1 = lsB + 2048 + wave * 512;

    floatx4 acc[4][4];
#pragma unroll
    for (int i = 0; i < 4; i++)
#pragma unroll
        for (int j = 0; j < 4; j++) {
            floatx4 zz = {0.f, 0.f, 0.f, 0.f};
            acc[i][j] = zz;
        }

    const int Kt = (MODE == 2) ? ((yb + 1) * 128) : K;
    for (int k0 = 0; k0 < Kt; k0 += 32) {
        __builtin_amdgcn_global_load_lds(GPTR(gA0), LPTR(lA0), 16, 0, 0);
        __builtin_amdgcn_global_load_lds(GPTR(gA1), LPTR(lA1), 16, 0, 0);
        __builtin_amdgcn_global_load_lds(GPTR(gB0), LPTR(lB0), 16, 0, 0);
        __builtin_amdgcn_global_load_lds(GPTR(gB1), LPTR(lB1), 16, 0, 0);
        gA0 += 32; gA1 += 32; gB0 += 32; gB1 += 32;
        __syncthreads();

        bf16x8 af[4], bfr[4];
#pragma unroll
        for (int i = 0; i < 4; i++) {
            af[i] = *(const bf16x8*)(lsA + (wm + i * 16 + l15) * 32 + quad * 8);
            bfr[i] = *(const bf16x8*)(lsB + (wn + i * 16 + l15) * 32 + quad * 8);
        }
#pragma unroll
        for (int i = 0; i < 4; i++)
#pragma unroll
            for (int j = 0; j < 4; j++)
                acc[i][j] = __builtin_amdgcn_mfma_f32_16x16x32_bf16(af[i], bfr[j], acc[i][j], 0, 0, 0);
        __syncthreads();
    }

    // ---- epilogue. C/D layout: col=lane&15, row=quad*4+r [verified m89/m91] ----
    const int colbase = blockIdx.x * 128;
    const int mq = quad * 4;

    if (MODE == 2) {
        // direct fp32 stores (64B/row-segment per 16-lane quad)
        float* Cf = (float*)Cv + (long long)z * sCz;
        const int m0 = yb * 128 + wm + mq;
        const int n0 = colbase + wn + l15;
#pragma unroll
        for (int j = 0; j < 4; j++)
#pragma unroll
            for (int i = 0; i < 4; i++)
#pragma unroll
                for (int r = 0; r < 4; r++)
                    Cf[(size_t)(m0 + i * 16 + r) * ldc + (n0 + j * 16)] = acc[i][j][r];
        return;
    }

    // bf16 outputs: stage chunks of 64 rows through LDS, coalesced 16B stores
    float addj[4];
#pragma unroll
    for (int j = 0; j < 4; j++)
        addj[j] = (MODE == 0) ? ((z == 0 ? b0 : (z == 1 ? b1 : b2))[colbase + wn + j * 16 + l15]) : 0.f;

    const bool transT = (MODE == 0) && (z == 2);
    u16* Cb = (u16*)Cv + (long long)z * sCz;

#pragma unroll
    for (int c = 0; c < 2; c++) {
        if ((wave >> 1) == c) {
#pragma unroll
            for (int i = 0; i < 4; i++)
#pragma unroll
                for (int j = 0; j < 4; j++)
#pragma unroll
                    for (int r = 0; r < 4; r++) {
                        int lr = i * 16 + mq + r;        // local row 0..63
                        int lc = wn + j * 16 + l15;      // local col 0..127
                        float v = acc[i][j][r];
                        v = (MODE == 0) ? (v + addj[j]) : (v * scale);
                        if (transT)
                            sm.epT[lc * 72 + lr] = f2bf(v);
                        else
                            sm.epN[lr * 136 + lc] = f2bf(v);
                    }
        }
        __syncthreads();
        if (!transT) {
#pragma unroll
            for (int k = 0; k < 4; k++) {
                int s2 = tid + 256 * k;        // 0..1023
                int row = s2 >> 4, cs = s2 & 15;
                uint4 val = *(const uint4*)&sm.epN[row * 136 + cs * 8];
                int m = yb * 128 + c * 64 + row;
                *(uint4*)(Cb + (size_t)m * ldc + colbase + cs * 8) = val;
            }
        } else {
            int gm0 = yb * 128 + c * 64;       // global token base of chunk
            int b = gm0 >> 11;
            int sb = gm0 & (SEQ - 1);
            u16* Vb = VtOut + (size_t)b * DIM * SEQ;
#pragma unroll
            for (int k = 0; k < 4; k++) {
                int s2 = tid + 256 * k;        // 0..1023
                int n = s2 >> 3, seg = s2 & 7;
                uint4 val = *(const uint4*)&sm.epT[n * 72 + seg * 8];
                *(uint4*)(Vb + (size_t)(colbase + n) * SEQ + sb + seg * 8) = val;
            }
        }
        __syncthreads();
    }
}

// -------- causal softmax: one row per block, register-resident, 1R+1W --------
__global__ __launch_bounds__(256) void softmax_causal(u16* __restrict__ S) {
    const int q = blockIdx.x, b = blockIdx.y, tid = threadIdx.x;
    u16* row = S + ((size_t)b * SEQ + q) * SEQ;
    const int L = q + 1;                    // valid keys
    const int Z = ((q >> 7) + 1) << 7;      // zero-fill bound = PV's K_eff
    const int k0 = tid * 8;
    __shared__ float redm[4], reds[4];

    uint4 rv = ((const uint4*)row)[tid];
    unsigned w[4] = {rv.x, rv.y, rv.z, rv.w};
    float f[8];
#pragma unroll
    for (int e = 0; e < 8; e++) {
        u16 h = (u16)((w[e >> 1] >> ((e & 1) * 16)) & 0xFFFFu);
        f[e] = (k0 + e < L) ? bf2f(h) : -3.0e38f;
    }
    float m = f[0];
#pragma unroll
    for (int e = 1; e < 8; e++) m = fmaxf(m, f[e]);
#pragma unroll
    for (int o = 32; o > 0; o >>= 1) m = fmaxf(m, __shfl_xor(m, o));
    if ((tid & 63) == 0) redm[tid >> 6] = m;
    __syncthreads();
    m = fmaxf(fmaxf(redm[0], redm[1]), fmaxf(redm[2], redm[3]));

    float p[8];
    float s = 0.f;
#pragma unroll
    for (int e = 0; e < 8; e++) {
        p[e] = (k0 + e < L) ? __expf(f[e] - m) : 0.f;
        s += p[e];
    }
#pragma unroll
    for (int o = 32; o > 0; o >>= 1) s += __shfl_xor(s, o);
    if ((tid & 63) == 0) reds[tid >> 6] = s;
    __syncthreads();
    s = reds[0] + reds[1] + reds[2] + reds[3];
    const float inv = 1.0f / s;

    if (k0 < Z) {
        unsigned o2[4];
#pragma unroll
        for (int e = 0; e < 4; e++) {
            unsigned lo = f2bf(p[2 * e] * inv);
            unsigned hi = f2bf(p[2 * e + 1] * inv);
            o2[e] = lo | (hi << 16);
        }
        uint4 ov = {o2[0], o2[1], o2[2], o2[3]};
        ((uint4*)row)[tid] = ov;
    }
}

extern "C" void kernel_launch(void* const* d_in, const int* in_sizes, int n_in,
                              void* d_out, int out_size, void* d_ws, size_t ws_size,
                              hipStream_t stream) {
    const float* x = (const float*)d_in[0];
    const float* Wq = (const float*)d_in[1];
    const float* bq = (const float*)d_in[2];
    const float* Wk = (const float*)d_in[3];
    const float* bk = (const float*)d_in[4];
    const float* Wv = (const float*)d_in[5];
    const float* bv = (const float*)d_in[6];
    float* out = (float*)d_out;

    char* ws = (char*)d_ws;
    const size_t MB = 1024ull * 1024ull;
    // layout: [0,32MB) early: xb(16MB)+Wt(6MB); late: S/P bf16 (32MB)
    //         [32,48) Q bf16 ; [48,64) K bf16 ; [64,80) Vt bf16 [d][s] per batch
    u16* S = (u16*)ws;
    u16* xb = (u16*)ws;
    u16* Wt = (u16*)(ws + 16 * MB);
    u16* QK = (u16*)(ws + 32 * MB);
    u16* Vt = (u16*)(ws + 64 * MB);
    const size_t MAT = (size_t)B_ * SEQ * DIM;  // 8M elements
    u16* Q = QK;
    u16* Km = QK + MAT;

    const float scale = 0.03125f;  // 1/sqrt(1024)

    convert_x<<<8192, 256, 0, stream>>>((const float4*)x, (ushort4*)xb);
    transpose_w<<<dim3(16, 16, 3), dim3(32, 8), 0, stream>>>(Wq, Wk, Wv, Wt);
    // QKV projection: C[8192,1024] = xb @ Wt^T + bias  (z=0:Q, 1:K, 2:V->Vt)
    gemm_bt<0><<<dim3(8, 64, 3), 256, 0, stream>>>(
        xb, Wt, QK, bq, bk, bv, Vt, DIM, DIM, DIM, DIM, 0.f,
        0LL, (long long)DIM * DIM, (long long)MAT);
    // scores: per batch, S[2048,2048] = Q @ K^T * scale (lower-tri, heavy-first)
    gemm_bt<1><<<dim3(16, 16, 4), 256, 0, stream>>>(
        Q, Km, S, nullptr, nullptr, nullptr, nullptr, DIM, DIM, SEQ, DIM, scale,
        (long long)SEQ * DIM, (long long)SEQ * DIM, (long long)SEQ * SEQ);
    softmax_causal<<<dim3(SEQ, B_), 256, 0, stream>>>(S);
    // context: per batch, out[2048,1024] = P @ Vt^T (K limited per q-tile)
    gemm_bt<2><<<dim3(8, 16, 4), 256, 0, stream>>>(
        S, Vt, out, nullptr, nullptr, nullptr, nullptr, SEQ, SEQ, DIM, SEQ, 1.f,
        (long long)SEQ * SEQ, (long long)DIM * SEQ, (long long)SEQ * DIM);
}

// Round 3
// 293.865 us; speedup vs baseline: 1.0835x; 1.0686x over previous
//
#include <hip/hip_runtime.h>

typedef unsigned short u16;
typedef __bf16 bf16x8 __attribute__((ext_vector_type(8)));
typedef float floatx4 __attribute__((ext_vector_type(4)));

#define B_ 4
#define SEQ 2048
#define DIM 1024

__device__ __forceinline__ u16 f2bf(float f) {
    unsigned u = __builtin_bit_cast(unsigned, f);
    u += 0x7FFFu + ((u >> 16) & 1u);
    return (u16)(u >> 16);
}
__device__ __forceinline__ float bf2f(u16 h) {
    unsigned u = ((unsigned)h) << 16;
    return __builtin_bit_cast(float, u);
}

#define GPTR(p) ((const __attribute__((address_space(1))) void*)(p))
#define LPTR(p) ((__attribute__((address_space(3))) void*)(p))

// ---------------- convert x fp32 -> bf16 ----------------
__global__ __launch_bounds__(256) void convert_x(const float4* __restrict__ x,
                                                 ushort4* __restrict__ xb) {
    int i = blockIdx.x * 256 + threadIdx.x;  // 2M float4s
    float4 v = x[i];
    ushort4 o;
    o.x = f2bf(v.x); o.y = f2bf(v.y); o.z = f2bf(v.z); o.w = f2bf(v.w);
    xb[i] = o;
}

// ---------------- transpose W [k][n] fp32 -> Wt [n][k] bf16 ----------------
__global__ __launch_bounds__(256) void transpose_w(const float* __restrict__ Wq,
                                                   const float* __restrict__ Wk,
                                                   const float* __restrict__ Wv,
                                                   u16* __restrict__ Wt) {
    __shared__ u16 t[64][66];
    const int z = blockIdx.z;
    const float* W = (z == 0) ? Wq : ((z == 1) ? Wk : Wv);
    u16* out = Wt + (size_t)z * DIM * DIM;
    const int tx = threadIdx.x, ty = threadIdx.y;  // (32,8)
    const int k0 = blockIdx.x * 64, n0 = blockIdx.y * 64;
#pragma unroll
    for (int j = 0; j < 8; j++) {
        int k = ty + 8 * j;
        float2 v = *(const float2*)(W + (size_t)(k0 + k) * DIM + n0 + 2 * tx);
        t[2 * tx][k] = f2bf(v.x);
        t[2 * tx + 1][k] = f2bf(v.y);
    }
    __syncthreads();
#pragma unroll
    for (int j = 0; j < 8; j++) {
        int n = ty + 8 * j;
        ushort2 o;
        o.x = t[n][2 * tx];
        o.y = t[n][2 * tx + 1];
        *(ushort2*)(out + (size_t)(n0 + n) * DIM + k0 + 2 * tx) = o;
    }
}

// ---- shared 128x128 bf16 MFMA mainloop, A [m][k], B transposed [n][k] ------
__device__ __forceinline__ void run_mainloop(
    const u16* __restrict__ Ab, const u16* __restrict__ Bb, int lda, int ldb,
    int Kt, u16* lsA, u16* lsB, int tid, int wave, int quad, int l15,
    int wm, int wn, floatx4 (&acc)[4][4]) {
    const int srow = tid >> 2;
    const int scol = (tid & 3) * 8;
    const u16* gA0 = Ab + (size_t)srow * lda + scol;
    const u16* gA1 = gA0 + (size_t)64 * lda;
    const u16* gB0 = Bb + (size_t)srow * ldb + scol;
    const u16* gB1 = gB0 + (size_t)64 * ldb;
    u16* lA0 = lsA + wave * 512;
    u16* lA1 = lsA + 2048 + wave * 512;
    u16* lB0 = lsB + wave * 512;
    u16* lB1 = lsB + 2048 + wave * 512;

#pragma unroll
    for (int i = 0; i < 4; i++)
#pragma unroll
        for (int j = 0; j < 4; j++) {
            floatx4 zz = {0.f, 0.f, 0.f, 0.f};
            acc[i][j] = zz;
        }

    for (int k0 = 0; k0 < Kt; k0 += 32) {
        __builtin_amdgcn_global_load_lds(GPTR(gA0), LPTR(lA0), 16, 0, 0);
        __builtin_amdgcn_global_load_lds(GPTR(gA1), LPTR(lA1), 16, 0, 0);
        __builtin_amdgcn_global_load_lds(GPTR(gB0), LPTR(lB0), 16, 0, 0);
        __builtin_amdgcn_global_load_lds(GPTR(gB1), LPTR(lB1), 16, 0, 0);
        gA0 += 32; gA1 += 32; gB0 += 32; gB1 += 32;
        __syncthreads();

        bf16x8 af[4], bfr[4];
#pragma unroll
        for (int i = 0; i < 4; i++) {
            af[i] = *(const bf16x8*)(lsA + (wm + i * 16 + l15) * 32 + quad * 8);
            bfr[i] = *(const bf16x8*)(lsB + (wn + i * 16 + l15) * 32 + quad * 8);
        }
#pragma unroll
        for (int i = 0; i < 4; i++)
#pragma unroll
            for (int j = 0; j < 4; j++)
                acc[i][j] = __builtin_amdgcn_mfma_f32_16x16x32_bf16(af[i], bfr[j], acc[i][j], 0, 0, 0);
        __syncthreads();
    }
}

// ---------------- QKV projection: C = xb @ Wt^T + bias ----------------------
// z=0 -> Q (bf16, direct stores), z=1 -> K (bf16, direct), z=2 -> V^T via LDS
__global__ __launch_bounds__(256) void gemm_qkv(
    const u16* __restrict__ A, const u16* __restrict__ Bt, u16* __restrict__ QK,
    const float* __restrict__ b0, const float* __restrict__ b1, const float* __restrict__ b2,
    u16* __restrict__ VtOut) {
    __shared__ union {
        u16 stage[2][128 * 32];  // 16 KB
        u16 epT[128 * 72];       // V^T epilogue staging (18.4 KB)
    } sm;
    const int tid = threadIdx.x;
    const int wave = tid >> 6, lane = tid & 63;
    const int quad = lane >> 4, l15 = lane & 15;
    const int wm = (wave >> 1) * 64, wn = (wave & 1) * 64;
    const int z = blockIdx.z, yb = blockIdx.y;

    const u16* Ab = A + (size_t)yb * 128 * DIM;
    const u16* Bb = Bt + (size_t)z * DIM * DIM + (size_t)blockIdx.x * 128 * DIM;
    floatx4 acc[4][4];
    run_mainloop(Ab, Bb, DIM, DIM, DIM, sm.stage[0], sm.stage[1],
                 tid, wave, quad, l15, wm, wn, acc);

    const int colbase = blockIdx.x * 128;
    const int mq = quad * 4;
    const float* bias = (z == 0) ? b0 : ((z == 1) ? b1 : b2);
    const int n0 = colbase + wn + l15;

    if (z < 2) {
        // direct scattered u16 stores (round-1 proven path)
        u16* Cb = QK + (size_t)z * B_ * SEQ * DIM;
        const int m0 = yb * 128 + wm + mq;
#pragma unroll
        for (int j = 0; j < 4; j++) {
            float bv_ = bias[n0 + j * 16];
#pragma unroll
            for (int i = 0; i < 4; i++)
#pragma unroll
                for (int r = 0; r < 4; r++)
                    Cb[(size_t)(m0 + i * 16 + r) * DIM + (n0 + j * 16)] = f2bf(acc[i][j][r] + bv_);
        }
        return;
    }

    // z == 2: write V^T [d][s] per batch via LDS transpose staging
    float addj[4];
#pragma unroll
    for (int j = 0; j < 4; j++) addj[j] = bias[n0 + j * 16];
#pragma unroll
    for (int c = 0; c < 2; c++) {
        __syncthreads();
        if ((wave >> 1) == c) {
#pragma unroll
            for (int i = 0; i < 4; i++)
#pragma unroll
                for (int j = 0; j < 4; j++)
#pragma unroll
                    for (int r = 0; r < 4; r++) {
                        int lr = i * 16 + mq + r;        // local row 0..63
                        int lc = wn + j * 16 + l15;      // local col 0..127
                        sm.epT[lc * 72 + lr] = f2bf(acc[i][j][r] + addj[j]);
                    }
        }
        __syncthreads();
        int gm0 = yb * 128 + c * 64;       // global token base of chunk
        int b = gm0 >> 11;
        int sb = gm0 & (SEQ - 1);
        u16* Vb = VtOut + (size_t)b * DIM * SEQ;
#pragma unroll
        for (int k = 0; k < 4; k++) {
            int s2 = tid + 256 * k;        // 0..1023
            int n = s2 >> 3, seg = s2 & 7;
            uint4 val = *(const uint4*)&sm.epT[n * 72 + seg * 8];
            *(uint4*)(Vb + (size_t)(colbase + n) * SEQ + sb + seg * 8) = val;
        }
    }
}

// ---------------- scores: S = Q @ K^T * scale (causal, heavy-first) ---------
__global__ __launch_bounds__(256) void gemm_scores(
    const u16* __restrict__ Q, const u16* __restrict__ K, u16* __restrict__ S,
    float scale) {
    const int yb = gridDim.y - 1 - blockIdx.y;
    if ((int)blockIdx.x > yb) return;  // fully-masked tile

    __shared__ u16 stage[2][128 * 32];
    const int tid = threadIdx.x;
    const int wave = tid >> 6, lane = tid & 63;
    const int quad = lane >> 4, l15 = lane & 15;
    const int wm = (wave >> 1) * 64, wn = (wave & 1) * 64;
    const int z = blockIdx.z;

    const u16* Ab = Q + (size_t)z * SEQ * DIM + (size_t)yb * 128 * DIM;
    const u16* Bb = K + (size_t)z * SEQ * DIM + (size_t)blockIdx.x * 128 * DIM;
    floatx4 acc[4][4];
    run_mainloop(Ab, Bb, DIM, DIM, DIM, stage[0], stage[1],
                 tid, wave, quad, l15, wm, wn, acc);

    u16* Cb = S + (size_t)z * SEQ * SEQ;
    const int m0 = yb * 128 + wm + quad * 4;
    const int n0 = blockIdx.x * 128 + wn + l15;
#pragma unroll
    for (int j = 0; j < 4; j++)
#pragma unroll
        for (int i = 0; i < 4; i++)
#pragma unroll
            for (int r = 0; r < 4; r++)
                Cb[(size_t)(m0 + i * 16 + r) * SEQ + (n0 + j * 16)] = f2bf(acc[i][j][r] * scale);
}

// ---------------- context: out = P @ Vt^T (K limited, heavy-first) ----------
__global__ __launch_bounds__(256) void gemm_pv(
    const u16* __restrict__ P, const u16* __restrict__ Vt, float* __restrict__ O) {
    const int yb = gridDim.y - 1 - blockIdx.y;
    __shared__ u16 stage[2][128 * 32];
    const int tid = threadIdx.x;
    const int wave = tid >> 6, lane = tid & 63;
    const int quad = lane >> 4, l15 = lane & 15;
    const int wm = (wave >> 1) * 64, wn = (wave & 1) * 64;
    const int z = blockIdx.z;

    const u16* Ab = P + (size_t)z * SEQ * SEQ + (size_t)yb * 128 * SEQ;
    const u16* Bb = Vt + (size_t)z * DIM * SEQ + (size_t)blockIdx.x * 128 * SEQ;
    const int Kt = (yb + 1) * 128;
    floatx4 acc[4][4];
    run_mainloop(Ab, Bb, SEQ, SEQ, Kt, stage[0], stage[1],
                 tid, wave, quad, l15, wm, wn, acc);

    float* Cf = O + (size_t)z * SEQ * DIM;
    const int m0 = yb * 128 + wm + quad * 4;
    const int n0 = blockIdx.x * 128 + wn + l15;
#pragma unroll
    for (int j = 0; j < 4; j++)
#pragma unroll
        for (int i = 0; i < 4; i++)
#pragma unroll
            for (int r = 0; r < 4; r++)
                Cf[(size_t)(m0 + i * 16 + r) * DIM + (n0 + j * 16)] = acc[i][j][r];
}

// -------- causal softmax: one row per block, register-resident, 1R+1W --------
__global__ __launch_bounds__(256) void softmax_causal(u16* __restrict__ S) {
    const int q = blockIdx.x, b = blockIdx.y, tid = threadIdx.x;
    u16* row = S + ((size_t)b * SEQ + q) * SEQ;
    const int L = q + 1;                    // valid keys
    const int Z = ((q >> 7) + 1) << 7;      // zero-fill bound = PV's K_eff
    const int k0 = tid * 8;
    __shared__ float redm[4], reds[4];

    uint4 rv = ((const uint4*)row)[tid];
    unsigned w[4] = {rv.x, rv.y, rv.z, rv.w};
    float f[8];
#pragma unroll
    for (int e = 0; e < 8; e++) {
        u16 h = (u16)((w[e >> 1] >> ((e & 1) * 16)) & 0xFFFFu);
        f[e] = (k0 + e < L) ? bf2f(h) : -3.0e38f;
    }
    float m = f[0];
#pragma unroll
    for (int e = 1; e < 8; e++) m = fmaxf(m, f[e]);
#pragma unroll
    for (int o = 32; o > 0; o >>= 1) m = fmaxf(m, __shfl_xor(m, o));
    if ((tid & 63) == 0) redm[tid >> 6] = m;
    __syncthreads();
    m = fmaxf(fmaxf(redm[0], redm[1]), fmaxf(redm[2], redm[3]));

    float p[8];
    float s = 0.f;
#pragma unroll
    for (int e = 0; e < 8; e++) {
        p[e] = (k0 + e < L) ? __expf(f[e] - m) : 0.f;
        s += p[e];
    }
#pragma unroll
    for (int o = 32; o > 0; o >>= 1) s += __shfl_xor(s, o);
    if ((tid & 63) == 0) reds[tid >> 6] = s;
    __syncthreads();
    s = reds[0] + reds[1] + reds[2] + reds[3];
    const float inv = 1.0f / s;

    if (k0 < Z) {
        unsigned o2[4];
#pragma unroll
        for (int e = 0; e < 4; e++) {
            unsigned lo = f2bf(p[2 * e] * inv);
            unsigned hi = f2bf(p[2 * e + 1] * inv);
            o2[e] = lo | (hi << 16);
        }
        uint4 ov = {o2[0], o2[1], o2[2], o2[3]};
        ((uint4*)row)[tid] = ov;
    }
}

extern "C" void kernel_launch(void* const* d_in, const int* in_sizes, int n_in,
                              void* d_out, int out_size, void* d_ws, size_t ws_size,
                              hipStream_t stream) {
    const float* x = (const float*)d_in[0];
    const float* Wq = (const float*)d_in[1];
    const float* bq = (const float*)d_in[2];
    const float* Wk = (const float*)d_in[3];
    const float* bk = (const float*)d_in[4];
    const float* Wv = (const float*)d_in[5];
    const float* bv = (const float*)d_in[6];
    float* out = (float*)d_out;

    char* ws = (char*)d_ws;
    const size_t MB = 1024ull * 1024ull;
    // layout: [0,32MB) early: xb(16MB)+Wt(6MB); late: S/P bf16 (32MB)
    //         [32,48) Q bf16 ; [48,64) K bf16 ; [64,80) Vt bf16 [d][s] per batch
    u16* S = (u16*)ws;
    u16* xb = (u16*)ws;
    u16* Wt = (u16*)(ws + 16 * MB);
    u16* QK = (u16*)(ws + 32 * MB);
    u16* Vt = (u16*)(ws + 64 * MB);
    const size_t MAT = (size_t)B_ * SEQ * DIM;  // 8M elements
    u16* Q = QK;
    u16* Km = QK + MAT;

    const float scale = 0.03125f;  // 1/sqrt(1024)

    convert_x<<<8192, 256, 0, stream>>>((const float4*)x, (ushort4*)xb);
    transpose_w<<<dim3(16, 16, 3), dim3(32, 8), 0, stream>>>(Wq, Wk, Wv, Wt);
    gemm_qkv<<<dim3(8, 64, 3), 256, 0, stream>>>(xb, Wt, QK, bq, bk, bv, Vt);
    gemm_scores<<<dim3(16, 16, 4), 256, 0, stream>>>(Q, Km, S, scale);
    softmax_causal<<<dim3(SEQ, B_), 256, 0, stream>>>(S);
    gemm_pv<<<dim3(8, 16, 4), 256, 0, stream>>>(S, Vt, out);
}

// Round 4
// 275.662 us; speedup vs baseline: 1.1551x; 1.0660x over previous
//
#include <hip/hip_runtime.h>

typedef unsigned short u16;
typedef __bf16 bf16x8 __attribute__((ext_vector_type(8)));
typedef float floatx4 __attribute__((ext_vector_type(4)));

#define B_ 4
#define SEQ 2048
#define DIM 1024

__device__ __forceinline__ u16 f2bf(float f) {
    unsigned u = __builtin_bit_cast(unsigned, f);
    u += 0x7FFFu + ((u >> 16) & 1u);
    return (u16)(u >> 16);
}
__device__ __forceinline__ float bf2f(u16 h) {
    unsigned u = ((unsigned)h) << 16;
    return __builtin_bit_cast(float, u);
}

#define GPTR(p) ((const __attribute__((address_space(1))) void*)(p))
#define LPTR(p) ((__attribute__((address_space(3))) void*)(p))

// ---------------- convert x fp32 -> bf16 ----------------
__global__ __launch_bounds__(256) void convert_x(const float4* __restrict__ x,
                                                 ushort4* __restrict__ xb) {
    int i = blockIdx.x * 256 + threadIdx.x;  // 2M float4s
    float4 v = x[i];
    ushort4 o;
    o.x = f2bf(v.x); o.y = f2bf(v.y); o.z = f2bf(v.z); o.w = f2bf(v.w);
    xb[i] = o;
}

// ---------------- transpose W [k][n] fp32 -> Wt [n][k] bf16 ----------------
__global__ __launch_bounds__(256) void transpose_w(const float* __restrict__ Wq,
                                                   const float* __restrict__ Wk,
                                                   const float* __restrict__ Wv,
                                                   u16* __restrict__ Wt) {
    __shared__ u16 t[64][66];
    const int z = blockIdx.z;
    const float* W = (z == 0) ? Wq : ((z == 1) ? Wk : Wv);
    u16* out = Wt + (size_t)z * DIM * DIM;
    const int tx = threadIdx.x, ty = threadIdx.y;  // (32,8)
    const int k0 = blockIdx.x * 64, n0 = blockIdx.y * 64;
#pragma unroll
    for (int j = 0; j < 8; j++) {
        int k = ty + 8 * j;
        float2 v = *(const float2*)(W + (size_t)(k0 + k) * DIM + n0 + 2 * tx);
        t[2 * tx][k] = f2bf(v.x);
        t[2 * tx + 1][k] = f2bf(v.y);
    }
    __syncthreads();
#pragma unroll
    for (int j = 0; j < 8; j++) {
        int n = ty + 8 * j;
        ushort2 o;
        o.x = t[n][2 * tx];
        o.y = t[n][2 * tx + 1];
        *(ushort2*)(out + (size_t)(n0 + n) * DIM + k0 + 2 * tx) = o;
    }
}

// ---- TMx128 bf16 MFMA mainloop, BK=64 as two 32-col panels ------------------
// A [m][k] row-major, B transposed [n][k]. TM in {64,128}.
// LDS: lsA = TM*64 u16 (2 panels of TM*32), lsB = 128*64 u16.
template <int TM>
__device__ __forceinline__ void mainloop64(
    const u16* __restrict__ Ab, const u16* __restrict__ Bb, int lda, int ldb,
    int Kt, u16* lsA, u16* lsB, int tid, int wave, int quad, int l15,
    int wm, int wn, floatx4 (&acc)[4][4]) {
    const int AI = TM / 32;  // fragment rows per wave (2 or 4)
    const int srow = tid >> 2;         // 0..63
    const int scol = (tid & 3) * 8;
    const u16* gA = Ab + (size_t)srow * lda + scol;
    const u16* gB = Bb + (size_t)srow * ldb + scol;

#pragma unroll
    for (int i = 0; i < 4; i++)
#pragma unroll
        for (int j = 0; j < 4; j++) {
            floatx4 zz = {0.f, 0.f, 0.f, 0.f};
            acc[i][j] = zz;
        }

    for (int k0 = 0; k0 < Kt; k0 += 64) {
        // stage A: panels h (k-halves), chunks c (64-row groups)
#pragma unroll
        for (int h = 0; h < 2; h++) {
            if (TM == 128) {
#pragma unroll
                for (int c = 0; c < 2; c++)
                    __builtin_amdgcn_global_load_lds(
                        GPTR(gA + (size_t)c * 64 * lda + h * 32),
                        LPTR(lsA + h * 4096 + c * 2048 + wave * 512), 16, 0, 0);
            } else {
                __builtin_amdgcn_global_load_lds(
                    GPTR(gA + h * 32),
                    LPTR(lsA + h * 2048 + wave * 512), 16, 0, 0);
            }
#pragma unroll
            for (int c = 0; c < 2; c++)
                __builtin_amdgcn_global_load_lds(
                    GPTR(gB + (size_t)c * 64 * ldb + h * 32),
                    LPTR(lsB + h * 4096 + c * 2048 + wave * 512), 16, 0, 0);
        }
        gA += 64; gB += 64;
        __syncthreads();

#pragma unroll
        for (int h = 0; h < 2; h++) {
            bf16x8 af[AI], bfr[4];
#pragma unroll
            for (int i = 0; i < AI; i++)
                af[i] = *(const bf16x8*)(lsA + h * (TM * 32) + (wm + i * 16 + l15) * 32 + quad * 8);
#pragma unroll
            for (int j = 0; j < 4; j++)
                bfr[j] = *(const bf16x8*)(lsB + h * 4096 + (wn + j * 16 + l15) * 32 + quad * 8);
#pragma unroll
            for (int i = 0; i < AI; i++)
#pragma unroll
                for (int j = 0; j < 4; j++)
                    acc[i][j] = __builtin_amdgcn_mfma_f32_16x16x32_bf16(af[i], bfr[j], acc[i][j], 0, 0, 0);
        }
        __syncthreads();
    }
}

// ---------------- QKV projection: C = xb @ Wt^T + bias ----------------------
// grid (24,64): z = x>>3 (Q,K,V), col-tile = x&7. Adjacent blocks share A-tile.
__global__ __launch_bounds__(256) void gemm_qkv(
    const u16* __restrict__ A, const u16* __restrict__ Bt, u16* __restrict__ QK,
    const float* __restrict__ b0, const float* __restrict__ b1, const float* __restrict__ b2,
    u16* __restrict__ VtOut) {
    __shared__ union {
        u16 stage[2][128 * 64];  // lsA, lsB (32 KB)
        u16 epT[128 * 72];       // V^T epilogue staging (18.4 KB)
    } sm;
    const int tid = threadIdx.x;
    const int wave = tid >> 6, lane = tid & 63;
    const int quad = lane >> 4, l15 = lane & 15;
    const int wm = (wave >> 1) * 64, wn = (wave & 1) * 64;
    const int z = blockIdx.x >> 3, xb8 = blockIdx.x & 7, yb = blockIdx.y;

    const u16* Ab = A + (size_t)yb * 128 * DIM;
    const u16* Bb = Bt + (size_t)z * DIM * DIM + (size_t)xb8 * 128 * DIM;
    floatx4 acc[4][4];
    mainloop64<128>(Ab, Bb, DIM, DIM, DIM, sm.stage[0], sm.stage[1],
                    tid, wave, quad, l15, wm, wn, acc);

    const int colbase = xb8 * 128;
    const int mq = quad * 4;
    const float* bias = (z == 0) ? b0 : ((z == 1) ? b1 : b2);
    const int n0 = colbase + wn + l15;

    if (z < 2) {
        u16* Cb = QK + (size_t)z * B_ * SEQ * DIM;
        const int m0 = yb * 128 + wm + mq;
#pragma unroll
        for (int j = 0; j < 4; j++) {
            float bv_ = bias[n0 + j * 16];
#pragma unroll
            for (int i = 0; i < 4; i++)
#pragma unroll
                for (int r = 0; r < 4; r++)
                    Cb[(size_t)(m0 + i * 16 + r) * DIM + (n0 + j * 16)] = f2bf(acc[i][j][r] + bv_);
        }
        return;
    }

    // z == 2: write V^T [d][s] per batch via LDS transpose staging
    float addj[4];
#pragma unroll
    for (int j = 0; j < 4; j++) addj[j] = bias[n0 + j * 16];
#pragma unroll
    for (int c = 0; c < 2; c++) {
        __syncthreads();
        if ((wave >> 1) == c) {
#pragma unroll
            for (int i = 0; i < 4; i++)
#pragma unroll
                for (int j = 0; j < 4; j++)
#pragma unroll
                    for (int r = 0; r < 4; r++) {
                        int lr = i * 16 + mq + r;        // local row 0..63
                        int lc = wn + j * 16 + l15;      // local col 0..127
                        sm.epT[lc * 72 + lr] = f2bf(acc[i][j][r] + addj[j]);
                    }
        }
        __syncthreads();
        int gm0 = yb * 128 + c * 64;       // global token base of chunk
        int b = gm0 >> 11;
        int sb = gm0 & (SEQ - 1);
        u16* Vb = VtOut + (size_t)b * DIM * SEQ;
#pragma unroll
        for (int k = 0; k < 4; k++) {
            int s2 = tid + 256 * k;        // 0..1023
            int n = s2 >> 3, seg = s2 & 7;
            uint4 val = *(const uint4*)&sm.epT[n * 72 + seg * 8];
            *(uint4*)(Vb + (size_t)(colbase + n) * SEQ + sb + seg * 8) = val;
        }
    }
}

// ------- scores: S = Q @ K^T * scale (64-row tiles, causal, heavy-first) ----
__global__ __launch_bounds__(256) void gemm_scores(
    const u16* __restrict__ Q, const u16* __restrict__ K, u16* __restrict__ S,
    float scale) {
    const int ym = gridDim.y - 1 - blockIdx.y;  // 0..31, heavy-first
    if ((int)blockIdx.x > (ym >> 1)) return;    // fully-masked tile

    __shared__ u16 lsA[64 * 64];   // 8 KB
    __shared__ u16 lsB[128 * 64];  // 16 KB
    const int tid = threadIdx.x;
    const int wave = tid >> 6, lane = tid & 63;
    const int quad = lane >> 4, l15 = lane & 15;
    const int wm = (wave >> 1) * 32, wn = (wave & 1) * 64;
    const int z = blockIdx.z;

    const u16* Ab = Q + (size_t)z * SEQ * DIM + (size_t)ym * 64 * DIM;
    const u16* Bb = K + (size_t)z * SEQ * DIM + (size_t)blockIdx.x * 128 * DIM;
    floatx4 acc[4][4];
    mainloop64<64>(Ab, Bb, DIM, DIM, DIM, lsA, lsB,
                   tid, wave, quad, l15, wm, wn, acc);

    u16* Cb = S + (size_t)z * SEQ * SEQ;
    const int m0 = ym * 64 + wm + quad * 4;
    const int n0 = blockIdx.x * 128 + wn + l15;
#pragma unroll
    for (int j = 0; j < 4; j++)
#pragma unroll
        for (int i = 0; i < 2; i++)
#pragma unroll
            for (int r = 0; r < 4; r++)
                Cb[(size_t)(m0 + i * 16 + r) * SEQ + (n0 + j * 16)] = f2bf(acc[i][j][r] * scale);
}

// ------- context: out = P @ Vt^T (64-row tiles, K limited, heavy-first) -----
__global__ __launch_bounds__(256) void gemm_pv(
    const u16* __restrict__ P, const u16* __restrict__ Vt, float* __restrict__ O) {
    const int ym = gridDim.y - 1 - blockIdx.y;  // 0..31, heavy-first
    __shared__ u16 lsA[64 * 64];
    __shared__ u16 lsB[128 * 64];
    const int tid = threadIdx.x;
    const int wave = tid >> 6, lane = tid & 63;
    const int quad = lane >> 4, l15 = lane & 15;
    const int wm = (wave >> 1) * 32, wn = (wave & 1) * 64;
    const int z = blockIdx.z;

    const u16* Ab = P + (size_t)z * SEQ * SEQ + (size_t)ym * 64 * SEQ;
    const u16* Bb = Vt + (size_t)z * DIM * SEQ + (size_t)blockIdx.x * 128 * SEQ;
    const int Kt = ((ym + 2) >> 1) * 128;  // keys needed by rows ym*64..+63
    floatx4 acc[4][4];
    mainloop64<64>(Ab, Bb, SEQ, SEQ, Kt, lsA, lsB,
                   tid, wave, quad, l15, wm, wn, acc);

    float* Cf = O + (size_t)z * SEQ * DIM;
    const int m0 = ym * 64 + wm + quad * 4;
    const int n0 = blockIdx.x * 128 + wn + l15;
#pragma unroll
    for (int j = 0; j < 4; j++)
#pragma unroll
        for (int i = 0; i < 2; i++)
#pragma unroll
            for (int r = 0; r < 4; r++)
                Cf[(size_t)(m0 + i * 16 + r) * DIM + (n0 + j * 16)] = acc[i][j][r];
}

// -------- causal softmax: one row per block, register-resident, 1R+1W --------
__global__ __launch_bounds__(256) void softmax_causal(u16* __restrict__ S) {
    const int q = blockIdx.x, b = blockIdx.y, tid = threadIdx.x;
    u16* row = S + ((size_t)b * SEQ + q) * SEQ;
    const int L = q + 1;                    // valid keys
    const int Z = ((q >> 7) + 1) << 7;      // zero-fill bound >= PV's K_eff
    const int k0 = tid * 8;
    __shared__ float redm[4], reds[4];

    uint4 rv = ((const uint4*)row)[tid];
    unsigned w[4] = {rv.x, rv.y, rv.z, rv.w};
    float f[8];
#pragma unroll
    for (int e = 0; e < 8; e++) {
        u16 h = (u16)((w[e >> 1] >> ((e & 1) * 16)) & 0xFFFFu);
        f[e] = (k0 + e < L) ? bf2f(h) : -3.0e38f;
    }
    float m = f[0];
#pragma unroll
    for (int e = 1; e < 8; e++) m = fmaxf(m, f[e]);
#pragma unroll
    for (int o = 32; o > 0; o >>= 1) m = fmaxf(m, __shfl_xor(m, o));
    if ((tid & 63) == 0) redm[tid >> 6] = m;
    __syncthreads();
    m = fmaxf(fmaxf(redm[0], redm[1]), fmaxf(redm[2], redm[3]));

    float p[8];
    float s = 0.f;
#pragma unroll
    for (int e = 0; e < 8; e++) {
        p[e] = (k0 + e < L) ? __expf(f[e] - m) : 0.f;
        s += p[e];
    }
#pragma unroll
    for (int o = 32; o > 0; o >>= 1) s += __shfl_xor(s, o);
    if ((tid & 63) == 0) reds[tid >> 6] = s;
    __syncthreads();
    s = reds[0] + reds[1] + reds[2] + reds[3];
    const float inv = 1.0f / s;

    if (k0 < Z) {
        unsigned o2[4];
#pragma unroll
        for (int e = 0; e < 4; e++) {
            unsigned lo = f2bf(p[2 * e] * inv);
            unsigned hi = f2bf(p[2 * e + 1] * inv);
            o2[e] = lo | (hi << 16);
        }
        uint4 ov = {o2[0], o2[1], o2[2], o2[3]};
        ((uint4*)row)[tid] = ov;
    }
}

extern "C" void kernel_launch(void* const* d_in, const int* in_sizes, int n_in,
                              void* d_out, int out_size, void* d_ws, size_t ws_size,
                              hipStream_t stream) {
    const float* x = (const float*)d_in[0];
    const float* Wq = (const float*)d_in[1];
    const float* bq = (const float*)d_in[2];
    const float* Wk = (const float*)d_in[3];
    const float* bk = (const float*)d_in[4];
    const float* Wv = (const float*)d_in[5];
    const float* bv = (const float*)d_in[6];
    float* out = (float*)d_out;

    char* ws = (char*)d_ws;
    const size_t MB = 1024ull * 1024ull;
    // layout: [0,32MB) early: xb(16MB)+Wt(6MB); late: S/P bf16 (32MB)
    //         [32,48) Q bf16 ; [48,64) K bf16 ; [64,80) Vt bf16 [d][s] per batch
    u16* S = (u16*)ws;
    u16* xb = (u16*)ws;
    u16* Wt = (u16*)(ws + 16 * MB);
    u16* QK = (u16*)(ws + 32 * MB);
    u16* Vt = (u16*)(ws + 64 * MB);
    const size_t MAT = (size_t)B_ * SEQ * DIM;  // 8M elements
    u16* Q = QK;
    u16* Km = QK + MAT;

    const float scale = 0.03125f;  // 1/sqrt(1024)

    convert_x<<<8192, 256, 0, stream>>>((const float4*)x, (ushort4*)xb);
    transpose_w<<<dim3(16, 16, 3), dim3(32, 8), 0, stream>>>(Wq, Wk, Wv, Wt);
    gemm_qkv<<<dim3(24, 64), 256, 0, stream>>>(xb, Wt, QK, bq, bk, bv, Vt);
    gemm_scores<<<dim3(16, 32, 4), 256, 0, stream>>>(Q, Km, S, scale);
    softmax_causal<<<dim3(SEQ, B_), 256, 0, stream>>>(S);
    gemm_pv<<<dim3(8, 32, 4), 256, 0, stream>>>(S, Vt, out);
}